// Round 7
// baseline (129.168 us; speedup 1.0000x reference)
//
#include <hip/hip_runtime.h>

#define T_DIM 20
#define K_DIM 50
#define V_DIM 50000
#define D_DIM 200
#define NEG_TOPK 20
#define M_DIM (K_DIM * NEG_TOPK)   // 1000 candidates per time slice
#define TEMP_INV (1.0f / 0.07f)
#define POOL_CAP 512
#define STATIC_THR 3.0f            // pool keeps all elements >= 3.0
#define BM_WORDS ((V_DIM + 31) / 32)  // 1563

// monotone key: order(key) == (value desc, index asc) matches jax.lax.top_k
__device__ __forceinline__ unsigned long long make_key(float f, int idx) {
  unsigned u  = __float_as_uint(f);
  unsigned mv = ((int)u < 0) ? ~u : (u | 0x80000000u);
  return ((unsigned long long)mv << 32) |
         (unsigned long long)(0xFFFFFFFFu - (unsigned)idx);
}

__device__ __forceinline__ unsigned long long wave_max_u64(unsigned long long k) {
#pragma unroll
  for (int off = 32; off; off >>= 1) {
    unsigned long long o = __shfl_xor(k, off, 64);
    if (o > k) k = o;
  }
  return k;
}

__device__ __forceinline__ float agent_load_f(const float* p) {
  return __hip_atomic_load(p, __ATOMIC_RELAXED, __HIP_MEMORY_SCOPE_AGENT);
}
__device__ __forceinline__ int agent_load_i(const int* p) {
  return __hip_atomic_load(p, __ATOMIC_RELAXED, __HIP_MEMORY_SCOPE_AGENT);
}
__device__ __forceinline__ void agent_store_f(float* p, float v) {
  __hip_atomic_store(p, v, __ATOMIC_RELAXED, __HIP_MEMORY_SCOPE_AGENT);
}

// ---------------------------------------------------------------------------
// Kernel 0: zero the ticket counters (poison-safe, deterministic).
// ---------------------------------------------------------------------------
__global__ void zero_kernel(int* __restrict__ cntT, int* __restrict__ gcount) {
  if (threadIdx.x < T_DIM) cntT[threadIdx.x] = 0;
  if (threadIdx.x == 0) *gcount = 0;
}

// ---------------------------------------------------------------------------
// Kernel 1: exact top-20 per row = t*K+k.
// Scan is EXPLICITLY 8-deep load-batched: 8 independent coalesced float4
// loads issued back-to-back per outer iteration (v[8], fully unrolled,
// static indices) so each wave keeps ~8 loads in flight -> ~256/CU, enough
// for the ~5KB/CU in-flight bytes HBM needs (R6 post-mortem: 1-deep gave
// exactly the predicted ~800 GB/s latency-bound rate).
// Elements >= 3.0 go to an LDS pool (E[|pool|]~67, Poisson); if
// 20<=|pool|<=512 the exact top-20 is in the pool. Selection on wave 0,
// barrier-free. Fallback (<20 or >512): exact 20-round block rescan.
// Then the 50th-finishing block of each t builds the dedup/valid list
// inline (ticket), overlapped with other blocks' scanning.
// ---------------------------------------------------------------------------
#define NV4   (V_DIM / 4)                 // 12500
#define BATCH 8
#define FULL_ITERS (NV4 / (512 * BATCH))  // 3  -> covers 12288
#define TAIL_BASE  (FULL_ITERS * 512 * BATCH)  // 12288, tail = 212

__global__ __launch_bounds__(512) void topk_bv_kernel(const float* __restrict__ beta,
                                                      const int* __restrict__ wc,
                                                      int* __restrict__ topk_idx,
                                                      int* __restrict__ vlist,
                                                      int* __restrict__ vcnt,
                                                      int* __restrict__ cntT) {
  const int row  = blockIdx.x;          // 0..999
  const int t    = row / K_DIM;
  const int tid  = threadIdx.x;
  const int lane = tid & 63;
  const int wid  = tid >> 6;
  const float4* __restrict__ b4 = (const float4*)(beta + (size_t)row * V_DIM);

  __shared__ unsigned long long pool[POOL_CAP];
  __shared__ int cnt;
  __shared__ unsigned long long wmax[8];
  __shared__ unsigned bm[BM_WORDS];
  __shared__ int bcnt;
  __shared__ int do_bv;
  if (tid == 0) cnt = 0;
  __syncthreads();

  // ---- scan: 8 loads in flight per wave ----
  for (int j = 0; j < FULL_ITERS; ++j) {
    const int ib = j * (512 * BATCH) + tid;
    float4 v0 = b4[ib + 0 * 512];
    float4 v1 = b4[ib + 1 * 512];
    float4 v2 = b4[ib + 2 * 512];
    float4 v3 = b4[ib + 3 * 512];
    float4 v4 = b4[ib + 4 * 512];
    float4 v5 = b4[ib + 5 * 512];
    float4 v6 = b4[ib + 6 * 512];
    float4 v7 = b4[ib + 7 * 512];
#define PROC(vq, q)                                                          \
    {                                                                        \
      float mx = fmaxf(fmaxf(vq.x, vq.y), fmaxf(vq.z, vq.w));                \
      if (mx >= STATIC_THR) {                                                \
        const int base = (ib + (q) * 512) * 4;                               \
        if (vq.x >= STATIC_THR) { int p = atomicAdd(&cnt, 1); if (p < POOL_CAP) pool[p] = make_key(vq.x, base + 0); } \
        if (vq.y >= STATIC_THR) { int p = atomicAdd(&cnt, 1); if (p < POOL_CAP) pool[p] = make_key(vq.y, base + 1); } \
        if (vq.z >= STATIC_THR) { int p = atomicAdd(&cnt, 1); if (p < POOL_CAP) pool[p] = make_key(vq.z, base + 2); } \
        if (vq.w >= STATIC_THR) { int p = atomicAdd(&cnt, 1); if (p < POOL_CAP) pool[p] = make_key(vq.w, base + 3); } \
      }                                                                      \
    }
    PROC(v0, 0) PROC(v1, 1) PROC(v2, 2) PROC(v3, 3)
    PROC(v4, 4) PROC(v5, 5) PROC(v6, 6) PROC(v7, 7)
#undef PROC
  }
  if (TAIL_BASE + tid < NV4) {          // tail: first 212 threads
    float4 v = b4[TAIL_BASE + tid];
    float mx = fmaxf(fmaxf(v.x, v.y), fmaxf(v.z, v.w));
    if (mx >= STATIC_THR) {
      const int base = (TAIL_BASE + tid) * 4;
      if (v.x >= STATIC_THR) { int p = atomicAdd(&cnt, 1); if (p < POOL_CAP) pool[p] = make_key(v.x, base + 0); }
      if (v.y >= STATIC_THR) { int p = atomicAdd(&cnt, 1); if (p < POOL_CAP) pool[p] = make_key(v.y, base + 1); }
      if (v.z >= STATIC_THR) { int p = atomicAdd(&cnt, 1); if (p < POOL_CAP) pool[p] = make_key(v.z, base + 2); }
      if (v.w >= STATIC_THR) { int p = atomicAdd(&cnt, 1); if (p < POOL_CAP) pool[p] = make_key(v.w, base + 3); }
    }
  }
  __syncthreads();
  const int count = cnt;

  if (count >= NEG_TOPK && count <= POOL_CAP) {
    if (wid == 0) {                    // wave-0-only selection, barrier-free
      unsigned long long kk[8];
#pragma unroll
      for (int j = 0; j < 8; ++j) {
        int p = lane + (j << 6);
        kk[j] = (p < count) ? pool[p] : 0ull;
      }
      unsigned long long kprev = ~0ull;
      for (int r = 0; r < NEG_TOPK; ++r) {
        unsigned long long b = 0ull;
#pragma unroll
        for (int j = 0; j < 8; ++j)
          if (kk[j] < kprev && kk[j] > b) b = kk[j];
        b = wave_max_u64(b);
        if (lane == 0)
          topk_idx[row * NEG_TOPK + r] =
              (int)(0xFFFFFFFFu - (unsigned)(b & 0xFFFFFFFFull));
        kprev = b;
      }
    }
  } else {
    // ---- fallback: 20 rounds of block argmax over the row (cached) ----
    unsigned long long kprev = ~0ull;
    for (int r = 0; r < NEG_TOPK; ++r) {
      unsigned long long b = 0ull;
      for (int i = tid; i < NV4; i += 512) {
        float4 v = b4[i];
        const int base = i * 4;
#pragma unroll
        for (int e = 0; e < 4; ++e) {
          float f = (e == 0) ? v.x : (e == 1) ? v.y : (e == 2) ? v.z : v.w;
          unsigned long long k = make_key(f, base + e);
          if (k < kprev && k > b) b = k;
        }
      }
      b = wave_max_u64(b);
      if (lane == 0) wmax[wid] = b;
      __syncthreads();
      unsigned long long bmax = wmax[0];
#pragma unroll
      for (int w = 1; w < 8; ++w) bmax = wmax[w] > bmax ? wmax[w] : bmax;
      if (tid == 0)
        topk_idx[row * NEG_TOPK + r] =
            (int)(0xFFFFFFFFu - (unsigned)(bmax & 0xFFFFFFFFull));
      kprev = bmax;
      __syncthreads();
    }
  }

  // ---- per-t ticket: 50th block of t builds the valid list inline ----
  if (tid == 0) {
    __threadfence();                       // release topk row
    do_bv = (atomicAdd(&cntT[t], 1) == K_DIM - 1);
  }
  __syncthreads();
  if (!do_bv) return;
  __threadfence();                         // acquire other blocks' rows

  for (int i = tid; i < BM_WORDS; i += 512) bm[i] = 0u;
  if (tid == 0) bcnt = 0;
  __syncthreads();
  for (int c = tid; c < M_DIM; c += 512) {
    int w = agent_load_i(&topk_idx[t * M_DIM + c]);
    if (wc[t * V_DIM + w] == 0) {
      unsigned bit = 1u << (w & 31);
      unsigned old = atomicOr(&bm[w >> 5], bit);
      if (!(old & bit)) {
        int p = atomicAdd(&bcnt, 1);
        vlist[t * M_DIM + p] = w;
      }
    }
  }
  __syncthreads();
  if (tid == 0) vcnt[t] = bcnt;
}

// ---------------------------------------------------------------------------
// Kernel 2: lse per row, XCD-pinned (all 50 blocks of a t on one XCD so the
// wemb gather working set (~240KB) stays in that XCD's 4MB L2); the
// last-finishing block computes the final scalar (global ticket).
// Grid = 1200: xcd = bid&7, slot = bid>>3; t = xcd + 8*(slot/50), k = slot%50;
// slots with t >= 20 are dummies and exit.
// ---------------------------------------------------------------------------
__global__ __launch_bounds__(256) void lse_final_kernel(const float* __restrict__ temb,
                                                        const float* __restrict__ wemb,
                                                        const int* __restrict__ vlist,
                                                        const int* __restrict__ vcnt,
                                                        float* __restrict__ lse,
                                                        int* __restrict__ gcount,
                                                        float* __restrict__ out) {
  const int xcd  = blockIdx.x & 7;
  const int slot = blockIdx.x >> 3;
  const int t    = xcd + ((slot / K_DIM) << 3);
  if (t >= T_DIM) return;               // dummy block
  const int k    = slot % K_DIM;
  const int row  = t * K_DIM + k;
  const int tid  = threadIdx.x;
  const int lane = tid & 63;
  const int wid  = tid >> 6;
  const int cnt  = vcnt[t];

  __shared__ float4 tvs[D_DIM / 4];  // 50 float4: topic embedding row
  __shared__ float  sim[M_DIM];      // also reused for final reduction
  __shared__ float  rbuf[8];
  __shared__ int    last_s;

  float lval = 0.0f;
  if (cnt > 0) {
    if (tid < D_DIM / 4)
      tvs[tid] = ((const float4*)(temb + (size_t)row * D_DIM))[tid];
    __syncthreads();

    const int l7 = lane & 7;
    const int g  = lane >> 3;          // candidate sub-slot 0..7 within wave
    for (int c0 = wid * 8; c0 < cnt; c0 += 32) {
      const int c = c0 + g;
      float acc = 0.f;
      if (c < cnt) {
        const int w = vlist[t * M_DIM + c];
        const float4* __restrict__ wr = (const float4*)(wemb + (size_t)w * D_DIM);
#pragma unroll
        for (int m = 0; m < 6; ++m) {        // d = l7 + 8m, < 50 for m<6
          const int d = l7 + (m << 3);
          float4 a = tvs[d];
          float4 b = wr[d];
          acc = fmaf(a.x, b.x, acc);
          acc = fmaf(a.y, b.y, acc);
          acc = fmaf(a.z, b.z, acc);
          acc = fmaf(a.w, b.w, acc);
        }
        if (l7 < 2) {                        // d in {48,49}
          const int d = l7 + 48;
          float4 a = tvs[d];
          float4 b = wr[d];
          acc = fmaf(a.x, b.x, acc);
          acc = fmaf(a.y, b.y, acc);
          acc = fmaf(a.z, b.z, acc);
          acc = fmaf(a.w, b.w, acc);
        }
      }
      acc += __shfl_xor(acc, 1, 64);
      acc += __shfl_xor(acc, 2, 64);
      acc += __shfl_xor(acc, 4, 64);
      if (l7 == 0 && c < cnt) sim[c] = acc * TEMP_INV;
    }
    __syncthreads();

    float m = -3.0e38f;
    for (int c = tid; c < cnt; c += 256) m = fmaxf(m, sim[c]);
#pragma unroll
    for (int off = 32; off; off >>= 1) m = fmaxf(m, __shfl_xor(m, off, 64));
    if (lane == 0) rbuf[wid] = m;
    __syncthreads();
    m = fmaxf(fmaxf(rbuf[0], rbuf[1]), fmaxf(rbuf[2], rbuf[3]));

    float s = 0.f;
    for (int c = tid; c < cnt; c += 256) s += expf(sim[c] - m);
#pragma unroll
    for (int off = 32; off; off >>= 1) s += __shfl_xor(s, off, 64);
    if (lane == 0) rbuf[4 + wid] = s;
    __syncthreads();
    lval = m + logf(rbuf[4] + rbuf[5] + rbuf[6] + rbuf[7]);
  }

  // ---- publish + global ticket; last block (of 1000) does the final ----
  if (tid == 0) {
    agent_store_f(&lse[row], lval);
    __threadfence();
    last_s = (atomicAdd(gcount, 1) == T_DIM * K_DIM - 1);
  }
  __syncthreads();
  if (!last_s) return;
  __threadfence();

  for (int r = tid; r < T_DIM * K_DIM; r += 256)
    sim[r] = agent_load_f(&lse[r]);
  __syncthreads();
  float loss = 0.f, flag = 0.f;
  if (tid < T_DIM) {
    if (agent_load_i(&vcnt[tid]) > 0) {
      float s = 0.f;
      for (int kk = 0; kk < K_DIM; ++kk) s += sim[tid * K_DIM + kk];
      loss = s * (1.0f / K_DIM);
      flag = 1.f;
    }
  }
  if (wid == 0) {
#pragma unroll
    for (int off = 32; off; off >>= 1) {
      loss += __shfl_down(loss, off, 64);
      flag += __shfl_down(flag, off, 64);
    }
    if (tid == 0)
      out[0] = (flag > 0.f) ? loss * (1.0f / fmaxf(flag, 1.f)) : 0.f;  // W=1
  }
}

// ---------------------------------------------------------------------------
extern "C" void kernel_launch(void* const* d_in, const int* in_sizes, int n_in,
                              void* d_out, int out_size, void* d_ws, size_t ws_size,
                              hipStream_t stream) {
  const int*   wc   = (const int*)d_in[0];    // time_wordcount [T,V] int32
  const float* beta = (const float*)d_in[1];  // beta [T,K,V] f32
  const float* temb = (const float*)d_in[2];  // topic_embeddings [T,K,D] f32
  const float* wemb = (const float*)d_in[3];  // word_embeddings [V,D] f32

  // ws layout: topk 80000 | vlist 80000 | vcnt 128 | cntT 128 | gcount 16 | lse 4000
  char* ws = (char*)d_ws;
  int*   topk_idx = (int*)(ws + 0);
  int*   vlist    = (int*)(ws + 80000);
  int*   vcnt     = (int*)(ws + 160000);
  int*   cntT     = (int*)(ws + 160128);
  int*   gcount   = (int*)(ws + 160256);
  float* lse      = (float*)(ws + 160272);
  float* out      = (float*)d_out;

  zero_kernel<<<1, 64, 0, stream>>>(cntT, gcount);
  topk_bv_kernel<<<T_DIM * K_DIM, 512, 0, stream>>>(beta, wc, topk_idx,
                                                    vlist, vcnt, cntT);
  lse_final_kernel<<<1200, 256, 0, stream>>>(temb, wemb, vlist, vcnt,
                                             lse, gcount, out);
}

// Round 8
// 86.642 us; speedup vs baseline: 1.4908x; 1.4908x over previous
//
#include <hip/hip_runtime.h>

#define T_DIM 20
#define K_DIM 50
#define V_DIM 50000
#define D_DIM 200
#define NEG_TOPK 20
#define M_DIM (K_DIM * NEG_TOPK)   // 1000 candidates per time slice
#define TEMP_INV (1.0f / 0.07f)
#define POOL_CAP 512
#define STATIC_THR 3.0f            // pool keeps all elements >= 3.0

// monotone key: order(key) == (value desc, index asc) matches jax.lax.top_k
__device__ __forceinline__ unsigned long long make_key(float f, int idx) {
  unsigned u  = __float_as_uint(f);
  unsigned mv = ((int)u < 0) ? ~u : (u | 0x80000000u);
  return ((unsigned long long)mv << 32) |
         (unsigned long long)(0xFFFFFFFFu - (unsigned)idx);
}

__device__ __forceinline__ unsigned long long wave_max_u64(unsigned long long k) {
#pragma unroll
  for (int off = 32; off; off >>= 1) {
    unsigned long long o = __shfl_xor(k, off, 64);
    if (o > k) k = o;
  }
  return k;
}

__device__ __forceinline__ float agent_load_f(const float* p) {
  return __hip_atomic_load(p, __ATOMIC_RELAXED, __HIP_MEMORY_SCOPE_AGENT);
}
__device__ __forceinline__ int agent_load_i(const int* p) {
  return __hip_atomic_load(p, __ATOMIC_RELAXED, __HIP_MEMORY_SCOPE_AGENT);
}
__device__ __forceinline__ void agent_store_f(float* p, float v) {
  __hip_atomic_store(p, v, __ATOMIC_RELAXED, __HIP_MEMORY_SCOPE_AGENT);
}

// ---------------------------------------------------------------------------
// Kernel 1: exact top-20 per row = t*K+k. BYTE-IDENTICAL to the R3 version
// (68.8 µs total) — R6/R7 proved that appending tail code to this kernel
// tanks the register allocator (48->24 VGPR) and serializes the load stream.
// DO NOT add code to this kernel.
// ---------------------------------------------------------------------------
__global__ __launch_bounds__(512) void topk_kernel(const float* __restrict__ beta,
                                                   int* __restrict__ topk_idx) {
  const int row  = blockIdx.x;          // 0..999
  const int tid  = threadIdx.x;
  const int lane = tid & 63;
  const int wid  = tid >> 6;
  const float4* __restrict__ b4 = (const float4*)(beta + (size_t)row * V_DIM);

  __shared__ unsigned long long pool[POOL_CAP];
  __shared__ int cnt;
  __shared__ unsigned long long wmax[8];
  if (tid == 0) cnt = 0;
  __syncthreads();

  // ---- scan: 1 compare per element, rare append ----
  for (int i = tid; i < V_DIM / 4; i += 512) {
    float4 v = b4[i];
    const int base = i * 4;
#pragma unroll
    for (int e = 0; e < 4; ++e) {
      float f = (e == 0) ? v.x : (e == 1) ? v.y : (e == 2) ? v.z : v.w;
      if (f >= STATIC_THR) {
        int p = atomicAdd(&cnt, 1);
        if (p < POOL_CAP) pool[p] = make_key(f, base + e);
      }
    }
  }
  __syncthreads();
  const int count = cnt;

  if (count >= NEG_TOPK && count <= POOL_CAP) {
    if (wid != 0) return;              // selection is wave-0-only, no barriers
    unsigned long long kk[8];
#pragma unroll
    for (int j = 0; j < 8; ++j) {
      int p = lane + (j << 6);
      kk[j] = (p < count) ? pool[p] : 0ull;
    }
    unsigned long long kprev = ~0ull;
    for (int r = 0; r < NEG_TOPK; ++r) {
      unsigned long long b = 0ull;
#pragma unroll
      for (int j = 0; j < 8; ++j)
        if (kk[j] < kprev && kk[j] > b) b = kk[j];
      b = wave_max_u64(b);
      if (lane == 0)
        topk_idx[row * NEG_TOPK + r] =
            (int)(0xFFFFFFFFu - (unsigned)(b & 0xFFFFFFFFull));
      kprev = b;
    }
  } else {
    // ---- fallback: 20 rounds of block argmax over the row (L2-hot) ----
    unsigned long long kprev = ~0ull;
    for (int r = 0; r < NEG_TOPK; ++r) {
      unsigned long long b = 0ull;
      for (int i = tid; i < V_DIM / 4; i += 512) {
        float4 v = b4[i];
        const int base = i * 4;
#pragma unroll
        for (int e = 0; e < 4; ++e) {
          float f = (e == 0) ? v.x : (e == 1) ? v.y : (e == 2) ? v.z : v.w;
          unsigned long long k = make_key(f, base + e);
          if (k < kprev && k > b) b = k;
        }
      }
      b = wave_max_u64(b);
      if (lane == 0) wmax[wid] = b;
      __syncthreads();
      unsigned long long bmax = wmax[0];
#pragma unroll
      for (int w = 1; w < 8; ++w) bmax = wmax[w] > bmax ? wmax[w] : bmax;
      if (tid == 0)
        topk_idx[row * NEG_TOPK + r] =
            (int)(0xFFFFFFFFu - (unsigned)(bmax & 0xFFFFFFFFull));
      kprev = bmax;
      __syncthreads();
    }
  }
}

// ---------------------------------------------------------------------------
// Kernel 2: per time slice t, unique valid candidates (wc==0, set semantics;
// which duplicate survives is irrelevant — identical sim rows). Block 0 also
// zeroes the lse ticket counter (kernel-boundary visibility to kernel 3).
// ---------------------------------------------------------------------------
#define BM_WORDS ((V_DIM + 31) / 32)    // 1563
__global__ __launch_bounds__(256) void build_valid_kernel(const int* __restrict__ wc,
                                                          const int* __restrict__ topk,
                                                          int* __restrict__ vlist,
                                                          int* __restrict__ vcnt,
                                                          int* __restrict__ gcount) {
  const int t = blockIdx.x;
  __shared__ unsigned bm[BM_WORDS];
  __shared__ int cnt;
  if (t == 0 && threadIdx.x == 0) *gcount = 0;
  for (int i = threadIdx.x; i < BM_WORDS; i += 256) bm[i] = 0u;
  if (threadIdx.x == 0) cnt = 0;
  __syncthreads();
  for (int c = threadIdx.x; c < M_DIM; c += 256) {
    int w = topk[t * M_DIM + c];
    if (wc[t * V_DIM + w] == 0) {
      unsigned bit = 1u << (w & 31);
      unsigned old = atomicOr(&bm[w >> 5], bit);
      if (!(old & bit)) {
        int p = atomicAdd(&cnt, 1);
        vlist[t * M_DIM + p] = w;
      }
    }
  }
  __syncthreads();
  if (threadIdx.x == 0) vcnt[t] = cnt;
}

// ---------------------------------------------------------------------------
// Kernel 3: lse per row, XCD-pinned (all 50 blocks of a t on one XCD so the
// wemb gather working set (~240KB) stays in that XCD's 4MB L2); the
// last-finishing block computes the final scalar (global ticket).
// Grid = 1200: xcd = bid&7, slot = bid>>3; t = xcd + 8*(slot/50), k = slot%50;
// slots with t >= 20 are dummies and exit before the ticket.
// ---------------------------------------------------------------------------
__global__ __launch_bounds__(256) void lse_final_kernel(const float* __restrict__ temb,
                                                        const float* __restrict__ wemb,
                                                        const int* __restrict__ vlist,
                                                        const int* __restrict__ vcnt,
                                                        float* __restrict__ lse,
                                                        int* __restrict__ gcount,
                                                        float* __restrict__ out) {
  const int xcd  = blockIdx.x & 7;
  const int slot = blockIdx.x >> 3;
  const int t    = xcd + ((slot / K_DIM) << 3);
  if (t >= T_DIM) return;               // dummy block
  const int k    = slot % K_DIM;
  const int row  = t * K_DIM + k;
  const int tid  = threadIdx.x;
  const int lane = tid & 63;
  const int wid  = tid >> 6;
  const int cnt  = vcnt[t];

  __shared__ float4 tvs[D_DIM / 4];  // 50 float4: topic embedding row
  __shared__ float  sim[M_DIM];      // also reused for final reduction
  __shared__ float  rbuf[8];
  __shared__ int    last_s;

  float lval = 0.0f;
  if (cnt > 0) {
    if (tid < D_DIM / 4)
      tvs[tid] = ((const float4*)(temb + (size_t)row * D_DIM))[tid];
    __syncthreads();

    const int l7 = lane & 7;
    const int g  = lane >> 3;          // candidate sub-slot 0..7 within wave
    for (int c0 = wid * 8; c0 < cnt; c0 += 32) {
      const int c = c0 + g;
      float acc = 0.f;
      if (c < cnt) {
        const int w = vlist[t * M_DIM + c];
        const float4* __restrict__ wr = (const float4*)(wemb + (size_t)w * D_DIM);
#pragma unroll
        for (int m = 0; m < 6; ++m) {        // d = l7 + 8m, < 50 for m<6
          const int d = l7 + (m << 3);
          float4 a = tvs[d];
          float4 b = wr[d];
          acc = fmaf(a.x, b.x, acc);
          acc = fmaf(a.y, b.y, acc);
          acc = fmaf(a.z, b.z, acc);
          acc = fmaf(a.w, b.w, acc);
        }
        if (l7 < 2) {                        // d in {48,49}
          const int d = l7 + 48;
          float4 a = tvs[d];
          float4 b = wr[d];
          acc = fmaf(a.x, b.x, acc);
          acc = fmaf(a.y, b.y, acc);
          acc = fmaf(a.z, b.z, acc);
          acc = fmaf(a.w, b.w, acc);
        }
      }
      acc += __shfl_xor(acc, 1, 64);
      acc += __shfl_xor(acc, 2, 64);
      acc += __shfl_xor(acc, 4, 64);
      if (l7 == 0 && c < cnt) sim[c] = acc * TEMP_INV;
    }
    __syncthreads();

    float m = -3.0e38f;
    for (int c = tid; c < cnt; c += 256) m = fmaxf(m, sim[c]);
#pragma unroll
    for (int off = 32; off; off >>= 1) m = fmaxf(m, __shfl_xor(m, off, 64));
    if (lane == 0) rbuf[wid] = m;
    __syncthreads();
    m = fmaxf(fmaxf(rbuf[0], rbuf[1]), fmaxf(rbuf[2], rbuf[3]));

    float s = 0.f;
    for (int c = tid; c < cnt; c += 256) s += expf(sim[c] - m);
#pragma unroll
    for (int off = 32; off; off >>= 1) s += __shfl_xor(s, off, 64);
    if (lane == 0) rbuf[4 + wid] = s;
    __syncthreads();
    lval = m + logf(rbuf[4] + rbuf[5] + rbuf[6] + rbuf[7]);
  }

  // ---- publish + global ticket; last block (of 1000) does the final ----
  if (tid == 0) {
    agent_store_f(&lse[row], lval);
    __threadfence();
    last_s = (atomicAdd(gcount, 1) == T_DIM * K_DIM - 1);
  }
  __syncthreads();
  if (!last_s) return;
  __threadfence();

  for (int r = tid; r < T_DIM * K_DIM; r += 256)
    sim[r] = agent_load_f(&lse[r]);
  __syncthreads();
  float loss = 0.f, flag = 0.f;
  if (tid < T_DIM) {
    if (agent_load_i(&vcnt[tid]) > 0) {
      float s = 0.f;
      for (int kk = 0; kk < K_DIM; ++kk) s += sim[tid * K_DIM + kk];
      loss = s * (1.0f / K_DIM);
      flag = 1.f;
    }
  }
  if (wid == 0) {
#pragma unroll
    for (int off = 32; off; off >>= 1) {
      loss += __shfl_down(loss, off, 64);
      flag += __shfl_down(flag, off, 64);
    }
    if (tid == 0)
      out[0] = (flag > 0.f) ? loss * (1.0f / fmaxf(flag, 1.f)) : 0.f;  // W=1
  }
}

// ---------------------------------------------------------------------------
extern "C" void kernel_launch(void* const* d_in, const int* in_sizes, int n_in,
                              void* d_out, int out_size, void* d_ws, size_t ws_size,
                              hipStream_t stream) {
  const int*   wc   = (const int*)d_in[0];    // time_wordcount [T,V] int32
  const float* beta = (const float*)d_in[1];  // beta [T,K,V] f32
  const float* temb = (const float*)d_in[2];  // topic_embeddings [T,K,D] f32
  const float* wemb = (const float*)d_in[3];  // word_embeddings [V,D] f32

  // ws layout: topk 80000 | vlist 80000 | vcnt 128 | gcount 16 | lse 4000
  char* ws = (char*)d_ws;
  int*   topk_idx = (int*)(ws + 0);
  int*   vlist    = (int*)(ws + 80000);
  int*   vcnt     = (int*)(ws + 160000);
  int*   gcount   = (int*)(ws + 160128);
  float* lse      = (float*)(ws + 160144);
  float* out      = (float*)d_out;

  topk_kernel<<<T_DIM * K_DIM, 512, 0, stream>>>(beta, topk_idx);
  build_valid_kernel<<<T_DIM, 256, 0, stream>>>(wc, topk_idx, vlist, vcnt, gcount);
  lse_final_kernel<<<1200, 256, 0, stream>>>(temb, wemb, vlist, vcnt,
                                             lse, gcount, out);
}

// Round 9
// 67.649 us; speedup vs baseline: 1.9094x; 1.2808x over previous
//
#include <hip/hip_runtime.h>

#define T_DIM 20
#define K_DIM 50
#define V_DIM 50000
#define D_DIM 200
#define NEG_TOPK 20
#define M_DIM (K_DIM * NEG_TOPK)   // 1000 candidates per time slice
#define TEMP_INV (1.0f / 0.07f)
#define POOL_CAP 512
#define STATIC_THR 3.0f            // pool keeps all elements >= 3.0

// monotone key: order(key) == (value desc, index asc) matches jax.lax.top_k
__device__ __forceinline__ unsigned long long make_key(float f, int idx) {
  unsigned u  = __float_as_uint(f);
  unsigned mv = ((int)u < 0) ? ~u : (u | 0x80000000u);
  return ((unsigned long long)mv << 32) |
         (unsigned long long)(0xFFFFFFFFu - (unsigned)idx);
}

__device__ __forceinline__ unsigned long long wave_max_u64(unsigned long long k) {
#pragma unroll
  for (int off = 32; off; off >>= 1) {
    unsigned long long o = __shfl_xor(k, off, 64);
    if (o > k) k = o;
  }
  return k;
}

// ---------------------------------------------------------------------------
// Kernel 1: exact top-20 per row = t*K+k. BYTE-IDENTICAL to the R3 version
// (68.8 µs total; compiler emits a deep-batched load stream here). R6/R7
// proved appending tail code tanks the register allocator (48->24 VGPR) and
// serializes the loads. DO NOT add code to this kernel.
// ---------------------------------------------------------------------------
__global__ __launch_bounds__(512) void topk_kernel(const float* __restrict__ beta,
                                                   int* __restrict__ topk_idx) {
  const int row  = blockIdx.x;          // 0..999
  const int tid  = threadIdx.x;
  const int lane = tid & 63;
  const int wid  = tid >> 6;
  const float4* __restrict__ b4 = (const float4*)(beta + (size_t)row * V_DIM);

  __shared__ unsigned long long pool[POOL_CAP];
  __shared__ int cnt;
  __shared__ unsigned long long wmax[8];
  if (tid == 0) cnt = 0;
  __syncthreads();

  // ---- scan: 1 compare per element, rare append ----
  for (int i = tid; i < V_DIM / 4; i += 512) {
    float4 v = b4[i];
    const int base = i * 4;
#pragma unroll
    for (int e = 0; e < 4; ++e) {
      float f = (e == 0) ? v.x : (e == 1) ? v.y : (e == 2) ? v.z : v.w;
      if (f >= STATIC_THR) {
        int p = atomicAdd(&cnt, 1);
        if (p < POOL_CAP) pool[p] = make_key(f, base + e);
      }
    }
  }
  __syncthreads();
  const int count = cnt;

  if (count >= NEG_TOPK && count <= POOL_CAP) {
    if (wid != 0) return;              // selection is wave-0-only, no barriers
    unsigned long long kk[8];
#pragma unroll
    for (int j = 0; j < 8; ++j) {
      int p = lane + (j << 6);
      kk[j] = (p < count) ? pool[p] : 0ull;
    }
    unsigned long long kprev = ~0ull;
    for (int r = 0; r < NEG_TOPK; ++r) {
      unsigned long long b = 0ull;
#pragma unroll
      for (int j = 0; j < 8; ++j)
        if (kk[j] < kprev && kk[j] > b) b = kk[j];
      b = wave_max_u64(b);
      if (lane == 0)
        topk_idx[row * NEG_TOPK + r] =
            (int)(0xFFFFFFFFu - (unsigned)(b & 0xFFFFFFFFull));
      kprev = b;
    }
  } else {
    // ---- fallback: 20 rounds of block argmax over the row (L2-hot) ----
    unsigned long long kprev = ~0ull;
    for (int r = 0; r < NEG_TOPK; ++r) {
      unsigned long long b = 0ull;
      for (int i = tid; i < V_DIM / 4; i += 512) {
        float4 v = b4[i];
        const int base = i * 4;
#pragma unroll
        for (int e = 0; e < 4; ++e) {
          float f = (e == 0) ? v.x : (e == 1) ? v.y : (e == 2) ? v.z : v.w;
          unsigned long long k = make_key(f, base + e);
          if (k < kprev && k > b) b = k;
        }
      }
      b = wave_max_u64(b);
      if (lane == 0) wmax[wid] = b;
      __syncthreads();
      unsigned long long bmax = wmax[0];
#pragma unroll
      for (int w = 1; w < 8; ++w) bmax = wmax[w] > bmax ? wmax[w] : bmax;
      if (tid == 0)
        topk_idx[row * NEG_TOPK + r] =
            (int)(0xFFFFFFFFu - (unsigned)(bmax & 0xFFFFFFFFull));
      kprev = bmax;
      __syncthreads();
    }
  }
}

// ---------------------------------------------------------------------------
// Kernel 2: per time slice t, unique valid candidates (wc==0, set semantics;
// which duplicate survives is irrelevant — identical sim rows). R3-verbatim.
// ---------------------------------------------------------------------------
#define BM_WORDS ((V_DIM + 31) / 32)    // 1563
__global__ __launch_bounds__(256) void build_valid_kernel(const int* __restrict__ wc,
                                                          const int* __restrict__ topk,
                                                          int* __restrict__ vlist,
                                                          int* __restrict__ vcnt) {
  const int t = blockIdx.x;
  __shared__ unsigned bm[BM_WORDS];
  __shared__ int cnt;
  for (int i = threadIdx.x; i < BM_WORDS; i += 256) bm[i] = 0u;
  if (threadIdx.x == 0) cnt = 0;
  __syncthreads();
  for (int c = threadIdx.x; c < M_DIM; c += 256) {
    int w = topk[t * M_DIM + c];
    if (wc[t * V_DIM + w] == 0) {
      unsigned bit = 1u << (w & 31);
      unsigned old = atomicOr(&bm[w >> 5], bit);
      if (!(old & bit)) {
        int p = atomicAdd(&cnt, 1);
        vlist[t * M_DIM + p] = w;
      }
    }
  }
  __syncthreads();
  if (threadIdx.x == 0) vcnt[t] = cnt;
}

// ---------------------------------------------------------------------------
// Kernel 3: lse per row — R3's kernel with ONE change: XCD-pinned grid.
// Grid = 1200: xcd = bid&7, slot = bid>>3; t = xcd + 8*(slot/50), k = slot%50
// -> all 50 blocks of a time slice land on one XCD, so the ~240KB gather
// working set is fetched from L3 once and re-served from that XCD's 4MB L2.
// Slots with t >= 20 are dummies and exit. No fences, no tickets (R4/R8:
// device-scope fences cost 12-18 µs — sync at kernel boundaries only).
// ---------------------------------------------------------------------------
__global__ __launch_bounds__(256) void lse_kernel(const float* __restrict__ temb,
                                                  const float* __restrict__ wemb,
                                                  const int* __restrict__ vlist,
                                                  const int* __restrict__ vcnt,
                                                  float* __restrict__ lse_out) {
  const int xcd  = blockIdx.x & 7;
  const int slot = blockIdx.x >> 3;
  const int t    = xcd + ((slot / K_DIM) << 3);
  if (t >= T_DIM) return;               // dummy block
  const int k    = slot % K_DIM;
  const int row  = t * K_DIM + k;
  const int tid  = threadIdx.x;
  const int lane = tid & 63;
  const int wid  = tid >> 6;
  const int cnt  = vcnt[t];

  __shared__ float4 tvs[D_DIM / 4];  // 50 float4: topic embedding row
  __shared__ float  sim[M_DIM];
  __shared__ float  rbuf[8];

  if (cnt == 0) {
    if (tid == 0) lse_out[row] = 0.0f;
    return;
  }

  if (tid < D_DIM / 4)
    tvs[tid] = ((const float4*)(temb + (size_t)row * D_DIM))[tid];
  __syncthreads();

  const int l7 = lane & 7;
  const int g  = lane >> 3;          // candidate sub-slot 0..7 within wave
  for (int c0 = wid * 8; c0 < cnt; c0 += 32) {
    const int c = c0 + g;
    float acc = 0.f;
    if (c < cnt) {
      const int w = vlist[t * M_DIM + c];
      const float4* __restrict__ wr = (const float4*)(wemb + (size_t)w * D_DIM);
#pragma unroll
      for (int m = 0; m < 6; ++m) {        // d = l7 + 8m, < 50 for m<6
        const int d = l7 + (m << 3);
        float4 a = tvs[d];
        float4 b = wr[d];
        acc = fmaf(a.x, b.x, acc);
        acc = fmaf(a.y, b.y, acc);
        acc = fmaf(a.z, b.z, acc);
        acc = fmaf(a.w, b.w, acc);
      }
      if (l7 < 2) {                        // d in {48,49}
        const int d = l7 + 48;
        float4 a = tvs[d];
        float4 b = wr[d];
        acc = fmaf(a.x, b.x, acc);
        acc = fmaf(a.y, b.y, acc);
        acc = fmaf(a.z, b.z, acc);
        acc = fmaf(a.w, b.w, acc);
      }
    }
    acc += __shfl_xor(acc, 1, 64);
    acc += __shfl_xor(acc, 2, 64);
    acc += __shfl_xor(acc, 4, 64);
    if (l7 == 0 && c < cnt) sim[c] = acc * TEMP_INV;
  }
  __syncthreads();

  float m = -3.0e38f;
  for (int c = tid; c < cnt; c += 256) m = fmaxf(m, sim[c]);
#pragma unroll
  for (int off = 32; off; off >>= 1) m = fmaxf(m, __shfl_xor(m, off, 64));
  if (lane == 0) rbuf[wid] = m;
  __syncthreads();
  m = fmaxf(fmaxf(rbuf[0], rbuf[1]), fmaxf(rbuf[2], rbuf[3]));

  float s = 0.f;
  for (int c = tid; c < cnt; c += 256) s += expf(sim[c] - m);
#pragma unroll
  for (int off = 32; off; off >>= 1) s += __shfl_xor(s, off, 64);
  if (lane == 0) rbuf[4 + wid] = s;
  __syncthreads();
  if (tid == 0) {
    float tot = rbuf[4] + rbuf[5] + rbuf[6] + rbuf[7];
    lse_out[row] = m + logf(tot);
  }
}

// ---------------------------------------------------------------------------
// Kernel 4: final scalar. loss = sum_t(mean_k lse) / count(t with any valid).
// ---------------------------------------------------------------------------
__global__ void final_kernel(const float* __restrict__ lse,
                             const int* __restrict__ vcnt,
                             float* __restrict__ out) {
  const int t = threadIdx.x;           // 64 threads, t < 20 active
  float loss = 0.f, flag = 0.f;
  if (t < T_DIM && vcnt[t] > 0) {
    float s = 0.f;
    for (int k = 0; k < K_DIM; ++k) s += lse[t * K_DIM + k];
    loss = s * (1.0f / K_DIM);
    flag = 1.f;
  }
#pragma unroll
  for (int off = 32; off; off >>= 1) {
    loss += __shfl_down(loss, off, 64);
    flag += __shfl_down(flag, off, 64);
  }
  if (t == 0)
    out[0] = (flag > 0.f) ? loss * (1.0f / fmaxf(flag, 1.f)) : 0.f;  // WEIGHT_UWE=1
}

// ---------------------------------------------------------------------------
extern "C" void kernel_launch(void* const* d_in, const int* in_sizes, int n_in,
                              void* d_out, int out_size, void* d_ws, size_t ws_size,
                              hipStream_t stream) {
  const int*   wc   = (const int*)d_in[0];    // time_wordcount [T,V] int32
  const float* beta = (const float*)d_in[1];  // beta [T,K,V] f32
  const float* temb = (const float*)d_in[2];  // topic_embeddings [T,K,D] f32
  const float* wemb = (const float*)d_in[3];  // word_embeddings [V,D] f32

  // ws layout: topk 80000B | vlist 80000B | vcnt 128B | lse 4000B
  char* ws = (char*)d_ws;
  int*   topk_idx = (int*)(ws + 0);
  int*   vlist    = (int*)(ws + 80000);
  int*   vcnt     = (int*)(ws + 160000);
  float* lse      = (float*)(ws + 160128);
  float* out      = (float*)d_out;

  topk_kernel<<<T_DIM * K_DIM, 512, 0, stream>>>(beta, topk_idx);
  build_valid_kernel<<<T_DIM, 256, 0, stream>>>(wc, topk_idx, vlist, vcnt);
  lse_kernel<<<1200, 256, 0, stream>>>(temb, wemb, vlist, vcnt, lse);
  final_kernel<<<1, 64, 0, stream>>>(lse, vcnt, out);
}